// Round 1
// baseline (755.135 us; speedup 1.0000x reference)
//
#include <hip/hip_runtime.h>
#include <stdint.h>
#include <stddef.h>

#define NNODES 50000
#define NEDGES 500000
#define DIM 256
#define NHEAD 8
#define HDIM 32
#define MPAD 50048   /* 391 * 128 */
#define NEGS 0.2f

typedef __attribute__((ext_vector_type(8))) short bf16x8;
typedef __attribute__((ext_vector_type(4))) float f32x4;
typedef __attribute__((ext_vector_type(4))) unsigned short u16x4;

__device__ __forceinline__ unsigned short f2bf(float f) {
    uint32_t u = __builtin_bit_cast(uint32_t, f);
    uint32_t r = (u + 0x7FFFu + ((u >> 16) & 1u)) >> 16;
    return (unsigned short)r;
}

__device__ __forceinline__ float leaky(float x) {
    return x > 0.0f ? x : NEGS * x;
}

__device__ __forceinline__ void gld_lds16(const unsigned short* g, unsigned short* l) {
    __builtin_amdgcn_global_load_lds(
        (const __attribute__((address_space(1))) void*)g,
        (__attribute__((address_space(3))) void*)l,
        16, 0, 0);
}

// ---------------- CSR build ----------------

__global__ __launch_bounds__(256) void count_kernel(const int* __restrict__ dst,
                                                    int* __restrict__ deg) {
    int i = blockIdx.x * 256 + threadIdx.x;
    if (i < NEDGES) atomicAdd(&deg[dst[i]], 1);
}

__global__ __launch_bounds__(1024) void scan_kernel(const int* __restrict__ deg,
                                                    int* __restrict__ rowptr,
                                                    int* __restrict__ cursor) {
    __shared__ int wsum[16];
    int t = threadIdx.x;
    int lane = t & 63, wv = t >> 6;
    int carry = 0;
    for (int base = 0; base < NNODES; base += 1024) {
        int idx = base + t;
        int v = (idx < NNODES) ? deg[idx] : 0;
        int x = v;
        #pragma unroll
        for (int off = 1; off < 64; off <<= 1) {
            int y = __shfl_up(x, off, 64);
            if (lane >= off) x += y;
        }
        if (lane == 63) wsum[wv] = x;
        __syncthreads();
        if (wv == 0) {
            int s = (lane < 16) ? wsum[lane] : 0;
            #pragma unroll
            for (int off = 1; off < 16; off <<= 1) {
                int y = __shfl_up(s, off, 64);
                if (lane >= off) s += y;
            }
            if (lane < 16) wsum[lane] = s;  // inclusive per-wave prefix
        }
        __syncthreads();
        int wave_excl = (wv == 0) ? 0 : wsum[wv - 1];
        int incl = x + wave_excl;
        int excl = incl - v;
        if (idx < NNODES) { rowptr[idx] = carry + excl; cursor[idx] = carry + excl; }
        int total = wsum[15];
        __syncthreads();
        carry += total;
    }
    if (t == 0) rowptr[NNODES] = carry;
}

__global__ __launch_bounds__(256) void fill_kernel(const int* __restrict__ src,
                                                   const int* __restrict__ dst,
                                                   int* __restrict__ cursor,
                                                   int* __restrict__ csr) {
    int i = blockIdx.x * 256 + threadIdx.x;
    if (i < NEDGES) {
        int pos = atomicAdd(&cursor[dst[i]], 1);
        csr[pos] = src[i];
    }
}

// ---------------- fp32 -> bf16 convert (with zero pad tail) ----------------

__global__ __launch_bounds__(256) void cvt_kernel(const float* __restrict__ x,
                                                  unsigned short* __restrict__ y,
                                                  int n_valid, int n_total) {
    int i = (blockIdx.x * 256 + threadIdx.x) * 4;
    if (i >= n_total) return;
    u16x4 o;
    if (i < n_valid) {
        const float4 v = *(const float4*)(x + i);
        o.x = f2bf(v.x); o.y = f2bf(v.y); o.z = f2bf(v.z); o.w = f2bf(v.w);
    } else {
        o.x = 0; o.y = 0; o.z = 0; o.w = 0;
    }
    *(u16x4*)(y + i) = o;
}

// ---------------- W [K][N] fp32 -> WT [N][K] bf16 ----------------

__global__ __launch_bounds__(256) void transpose_cvt(const float* __restrict__ W,
                                                     unsigned short* __restrict__ WT) {
    __shared__ float tile[32][33];
    int bx = blockIdx.x;  // n tile
    int by = blockIdx.y;  // k tile
    int tx = threadIdx.x & 31, ty = threadIdx.x >> 5;  // 32 x 8
    #pragma unroll
    for (int j = 0; j < 4; ++j)
        tile[ty + j * 8][tx] = W[(by * 32 + ty + j * 8) * DIM + bx * 32 + tx];
    __syncthreads();
    #pragma unroll
    for (int j = 0; j < 4; ++j)
        WT[(bx * 32 + ty + j * 8) * DIM + by * 32 + tx] = f2bf(tile[tx][ty + j * 8]);
}

// ---------------- GEMM: C[M][256] = A[M][256] @ W, via BT[n][k]=W[k][n] ----------------
// 128x128 block tile, 4 waves in 2x2, each wave 64x64 via 4x4 of 16x16x32 MFMA.

__global__ __launch_bounds__(256) void gemm_kernel(const unsigned short* __restrict__ A,
                                                   const unsigned short* __restrict__ BT,
                                                   float* __restrict__ C,
                                                   const float* __restrict__ bias) {
    __shared__ __align__(16) unsigned short As[128 * 32];
    __shared__ __align__(16) unsigned short Bs[128 * 32];
    int tid = threadIdx.x;
    int wave = tid >> 6, lane = tid & 63;
    int row0 = blockIdx.x * 128;
    int col0 = blockIdx.y * 128;
    int wm = (wave >> 1) * 64;
    int wn = (wave & 1) * 64;

    f32x4 acc[4][4] = {};

    int fr = lane & 15;
    int kg = (lane >> 4) * 8;

    for (int k0 = 0; k0 < DIM; k0 += 32) {
        // stage A and B tiles: each 128 rows x 32 cols bf16 (8KB each)
        #pragma unroll
        for (int r = 0; r < 2; ++r) {
            int row = r * 64 + (tid >> 2);
            int chunk = tid & 3;
            gld_lds16(A + (size_t)(row0 + row) * DIM + k0 + chunk * 8,
                      As + row * 32 + chunk * 8);
            gld_lds16(BT + (size_t)(col0 + row) * DIM + k0 + chunk * 8,
                      Bs + row * 32 + chunk * 8);
        }
        __syncthreads();

        bf16x8 a_frag[4], b_frag[4];
        #pragma unroll
        for (int i = 0; i < 4; ++i) {
            a_frag[i] = *(const bf16x8*)(As + (wm + i * 16 + fr) * 32 + kg);
            b_frag[i] = *(const bf16x8*)(Bs + (wn + i * 16 + fr) * 32 + kg);
        }
        #pragma unroll
        for (int i = 0; i < 4; ++i)
            #pragma unroll
            for (int j = 0; j < 4; ++j)
                acc[i][j] = __builtin_amdgcn_mfma_f32_16x16x32_bf16(
                    a_frag[i], b_frag[j], acc[i][j], 0, 0, 0);
        __syncthreads();
    }

    int rg = (lane >> 4) * 4;
    #pragma unroll
    for (int i = 0; i < 4; ++i) {
        #pragma unroll
        for (int j = 0; j < 4; ++j) {
            int n = col0 + wn + j * 16 + fr;
            float bv = bias ? bias[n] : 0.0f;
            #pragma unroll
            for (int r = 0; r < 4; ++r) {
                int m = row0 + wm + i * 16 + rg + r;
                C[(size_t)m * DIM + n] = acc[i][j][r] + bv;
            }
        }
    }
}

// ---------------- el/er: [N,H] dots of h rows with al/ar ----------------

__global__ __launch_bounds__(256) void eler_kernel(const float* __restrict__ Hf,
                                                   const float* __restrict__ al,
                                                   const float* __restrict__ ar,
                                                   float* __restrict__ el,
                                                   float* __restrict__ er) {
    int n = blockIdx.x;
    int t = threadIdx.x;
    float h = Hf[(size_t)n * DIM + t];
    float x = h * al[t];
    float y = h * ar[t];
    #pragma unroll
    for (int off = 16; off >= 1; off >>= 1) {
        x += __shfl_xor(x, off, 64);
        y += __shfl_xor(y, off, 64);
    }
    if ((t & 31) == 0) {
        int head = t >> 5;
        el[n * NHEAD + head] = x;
        er[n * NHEAD + head] = y;
    }
}

// ---------------- edge softmax + aggregation (one block per dst node) ----------------

__global__ __launch_bounds__(256) void agg_kernel(const float* __restrict__ Hf,
                                                  const float* __restrict__ el,
                                                  const float* __restrict__ er,
                                                  const int* __restrict__ rowptr,
                                                  const int* __restrict__ csr,
                                                  const float* __restrict__ bias,
                                                  float* __restrict__ out) {
    int v = blockIdx.x;
    int t = threadIdx.x;
    int head = t >> 5;
    float er_v = er[v * NHEAD + head];
    float el_v = el[v * NHEAD + head];
    int beg = rowptr[v], end = rowptr[v + 1];

    // pass 1: max over neighborhood (incl. self loop)
    float e_self = leaky(el_v + er_v);
    float m = e_self;
    for (int i = beg; i < end; ++i) {
        int u = csr[i];
        float e = leaky(el[u * NHEAD + head] + er_v);
        m = fmaxf(m, e);
    }

    // pass 2: exp-sum + weighted feature accumulation
    float a = __expf(e_self - m);
    float z = a;
    float acc = a * Hf[(size_t)v * DIM + t];
    for (int i = beg; i < end; ++i) {
        int u = csr[i];
        float e = leaky(el[u * NHEAD + head] + er_v);
        float w = __expf(e - m);
        z += w;
        acc += w * Hf[(size_t)u * DIM + t];
    }
    float o = acc / z + bias[t];
    out[(size_t)v * DIM + t] = leaky(o);
}

// ---------------- launch ----------------

static inline size_t align256(size_t x) { return (x + 255) & ~(size_t)255; }

extern "C" void kernel_launch(void* const* d_in, const int* in_sizes, int n_in,
                              void* d_out, int out_size, void* d_ws, size_t ws_size,
                              hipStream_t stream) {
    const float* feats  = (const float*)d_in[0];
    const int*   src    = (const int*)d_in[1];
    const int*   dst    = (const int*)d_in[2];
    const float* proj_W = (const float*)d_in[3];
    const float* proj_b = (const float*)d_in[4];
    const float* W1     = (const float*)d_in[5];
    const float* al1    = (const float*)d_in[6];
    const float* ar1    = (const float*)d_in[7];
    const float* b1     = (const float*)d_in[8];
    const float* W2     = (const float*)d_in[9];
    const float* al2    = (const float*)d_in[10];
    const float* ar2    = (const float*)d_in[11];
    const float* b2     = (const float*)d_in[12];
    float* out = (float*)d_out;

    uint8_t* w = (uint8_t*)d_ws;
    float* X  = (float*)w;            w += align256((size_t)MPAD * DIM * 4);
    float* Hf = (float*)w;            w += align256((size_t)MPAD * DIM * 4);
    unsigned short* Abf = (unsigned short*)w; w += align256((size_t)MPAD * DIM * 2);
    unsigned short* WT  = (unsigned short*)w; w += align256((size_t)DIM * DIM * 2);
    float* el = (float*)w;            w += align256((size_t)NNODES * NHEAD * 4);
    float* er = (float*)w;            w += align256((size_t)NNODES * NHEAD * 4);
    int* deg    = (int*)w;            w += align256((size_t)NNODES * 4);
    int* rowptr = (int*)w;            w += align256((size_t)(NNODES + 1) * 4);
    int* cursor = (int*)w;            w += align256((size_t)NNODES * 4);
    int* csr    = (int*)w;            w += align256((size_t)NEDGES * 4);

    const int edge_blocks = (NEDGES + 255) / 256;
    const int cvt_total = MPAD * DIM;
    const int cvt_blocks = cvt_total / 4 / 256;
    const dim3 gemm_grid(MPAD / 128, DIM / 128);

    // CSR build
    hipMemsetAsync(deg, 0, (size_t)NNODES * 4, stream);
    count_kernel<<<edge_blocks, 256, 0, stream>>>(dst, deg);
    scan_kernel<<<1, 1024, 0, stream>>>(deg, rowptr, cursor);
    fill_kernel<<<edge_blocks, 256, 0, stream>>>(src, dst, cursor, csr);

    // projection: X = feats @ proj_W + proj_b
    cvt_kernel<<<cvt_blocks, 256, 0, stream>>>(feats, Abf, NNODES * DIM, cvt_total);
    transpose_cvt<<<dim3(8, 8), 256, 0, stream>>>(proj_W, WT);
    gemm_kernel<<<gemm_grid, 256, 0, stream>>>(Abf, WT, X, proj_b);

    // layer 1
    cvt_kernel<<<cvt_blocks, 256, 0, stream>>>(X, Abf, NNODES * DIM, cvt_total);
    transpose_cvt<<<dim3(8, 8), 256, 0, stream>>>(W1, WT);
    gemm_kernel<<<gemm_grid, 256, 0, stream>>>(Abf, WT, Hf, nullptr);
    eler_kernel<<<NNODES, 256, 0, stream>>>(Hf, al1, ar1, el, er);
    agg_kernel<<<NNODES, 256, 0, stream>>>(Hf, el, er, rowptr, csr, b1, X);

    // layer 2
    cvt_kernel<<<cvt_blocks, 256, 0, stream>>>(X, Abf, NNODES * DIM, cvt_total);
    transpose_cvt<<<dim3(8, 8), 256, 0, stream>>>(W2, WT);
    gemm_kernel<<<gemm_grid, 256, 0, stream>>>(Abf, WT, Hf, nullptr);
    eler_kernel<<<NNODES, 256, 0, stream>>>(Hf, al2, ar2, el, er);
    agg_kernel<<<NNODES, 256, 0, stream>>>(Hf, el, er, rowptr, csr, b2, out);
}

// Round 2
// 371.146 us; speedup vs baseline: 2.0346x; 2.0346x over previous
//
#include <hip/hip_runtime.h>
#include <stdint.h>
#include <stddef.h>

#define NNODES 50000
#define NEDGES 500000
#define DIM 256
#define NHEAD 8
#define HDIM 32
#define MPAD 50048   /* 391 * 128 */
#define NEGS 0.2f
#define SCAN_BLOCKS 196  /* ceil(50000/256) */

typedef __attribute__((ext_vector_type(8))) short bf16x8;
typedef __attribute__((ext_vector_type(4))) float f32x4;
typedef __attribute__((ext_vector_type(4))) unsigned short u16x4;

__device__ __forceinline__ unsigned short f2bf(float f) {
    uint32_t u = __builtin_bit_cast(uint32_t, f);
    uint32_t r = (u + 0x7FFFu + ((u >> 16) & 1u)) >> 16;
    return (unsigned short)r;
}

__device__ __forceinline__ float bf2f(unsigned short u) {
    return __builtin_bit_cast(float, (uint32_t)u << 16);
}

__device__ __forceinline__ float leaky(float x) {
    return x > 0.0f ? x : NEGS * x;
}

__device__ __forceinline__ void gld_lds16(const unsigned short* g, unsigned short* l) {
    __builtin_amdgcn_global_load_lds(
        (const __attribute__((address_space(1))) void*)g,
        (__attribute__((address_space(3))) void*)l,
        16, 0, 0);
}

// ---------------- CSR build ----------------

__global__ __launch_bounds__(256) void count_kernel(const int* __restrict__ dst,
                                                    int* __restrict__ deg) {
    int i = blockIdx.x * 256 + threadIdx.x;
    if (i < NEDGES) atomicAdd(&deg[dst[i]], 1);
}

// phase A: per-256-block sums of deg
__global__ __launch_bounds__(256) void scanA_kernel(const int* __restrict__ deg,
                                                    int* __restrict__ bsum) {
    __shared__ int ws[4];
    int t = threadIdx.x;
    int idx = blockIdx.x * 256 + t;
    int v = (idx < NNODES) ? deg[idx] : 0;
    int x = v;
    #pragma unroll
    for (int off = 1; off < 64; off <<= 1) x += __shfl_xor(x, off, 64);
    if ((t & 63) == 0) ws[t >> 6] = x;
    __syncthreads();
    if (t == 0) bsum[blockIdx.x] = ws[0] + ws[1] + ws[2] + ws[3];
}

// phase B: exclusive scan of SCAN_BLOCKS block sums (single block)
__global__ __launch_bounds__(256) void scanB_kernel(const int* __restrict__ bsum,
                                                    int* __restrict__ boff,
                                                    int* __restrict__ rowptr) {
    __shared__ int s[256];
    int t = threadIdx.x;
    int v = (t < SCAN_BLOCKS) ? bsum[t] : 0;
    s[t] = v;
    __syncthreads();
    #pragma unroll
    for (int off = 1; off < 256; off <<= 1) {
        int y = (t >= off) ? s[t - off] : 0;
        __syncthreads();
        s[t] += y;
        __syncthreads();
    }
    if (t < SCAN_BLOCKS) boff[t] = s[t] - v;  // exclusive
    if (t == 0) rowptr[NNODES] = NEDGES;
}

// phase C: per-block exclusive scan + block offset -> rowptr, cursor
__global__ __launch_bounds__(256) void scanC_kernel(const int* __restrict__ deg,
                                                    const int* __restrict__ boff,
                                                    int* __restrict__ rowptr,
                                                    int* __restrict__ cursor) {
    __shared__ int ws[4];
    int t = threadIdx.x;
    int lane = t & 63, wv = t >> 6;
    int idx = blockIdx.x * 256 + t;
    int v = (idx < NNODES) ? deg[idx] : 0;
    int x = v;
    #pragma unroll
    for (int off = 1; off < 64; off <<= 1) {
        int y = __shfl_up(x, off, 64);
        if (lane >= off) x += y;
    }
    if (lane == 63) ws[wv] = x;
    __syncthreads();
    int wadd = 0;
    #pragma unroll
    for (int k = 0; k < 4; ++k) if (k < wv) wadd += ws[k];
    int excl = x - v + wadd + boff[blockIdx.x];
    if (idx < NNODES) { rowptr[idx] = excl; cursor[idx] = excl; }
}

__global__ __launch_bounds__(256) void fill_kernel(const int* __restrict__ src,
                                                   const int* __restrict__ dst,
                                                   int* __restrict__ cursor,
                                                   int* __restrict__ csr) {
    int i = blockIdx.x * 256 + threadIdx.x;
    if (i < NEDGES) {
        int pos = atomicAdd(&cursor[dst[i]], 1);
        csr[pos] = src[i];
    }
}

// ---------------- fp32 -> bf16 convert (valid region only) ----------------

__global__ __launch_bounds__(256) void cvt_kernel(const float* __restrict__ x,
                                                  unsigned short* __restrict__ y) {
    int i = (blockIdx.x * 256 + threadIdx.x) * 4;
    const float4 v = *(const float4*)(x + i);
    u16x4 o;
    o.x = f2bf(v.x); o.y = f2bf(v.y); o.z = f2bf(v.z); o.w = f2bf(v.w);
    *(u16x4*)(y + i) = o;
}

// ---------------- W [K][N] fp32 -> WT [N][K] bf16 ----------------

__global__ __launch_bounds__(256) void transpose_cvt(const float* __restrict__ W,
                                                     unsigned short* __restrict__ WT) {
    __shared__ float tile[32][33];
    int bx = blockIdx.x;  // n tile
    int by = blockIdx.y;  // k tile
    int tx = threadIdx.x & 31, ty = threadIdx.x >> 5;  // 32 x 8
    #pragma unroll
    for (int j = 0; j < 4; ++j)
        tile[ty + j * 8][tx] = W[(by * 32 + ty + j * 8) * DIM + bx * 32 + tx];
    __syncthreads();
    #pragma unroll
    for (int j = 0; j < 4; ++j)
        WT[(bx * 32 + ty + j * 8) * DIM + by * 32 + tx] = f2bf(tile[tx][ty + j * 8]);
}

// ---------------- GEMM: Cb[M][256](bf16) = A[M][256](bf16) @ W (+bias) ----------------
// 128x128 block tile, 4 waves in 2x2, each wave 64x64 via 4x4 of 16x16x32 MFMA.

__global__ __launch_bounds__(256) void gemm_kernel(const unsigned short* __restrict__ A,
                                                   const unsigned short* __restrict__ BT,
                                                   unsigned short* __restrict__ Cb,
                                                   const float* __restrict__ bias) {
    __shared__ __align__(16) unsigned short As[128 * 32];
    __shared__ __align__(16) unsigned short Bs[128 * 32];
    int tid = threadIdx.x;
    int wave = tid >> 6, lane = tid & 63;
    int row0 = blockIdx.x * 128;
    int col0 = blockIdx.y * 128;
    int wm = (wave >> 1) * 64;
    int wn = (wave & 1) * 64;

    f32x4 acc[4][4] = {};

    int fr = lane & 15;
    int kg = (lane >> 4) * 8;

    for (int k0 = 0; k0 < DIM; k0 += 32) {
        #pragma unroll
        for (int r = 0; r < 2; ++r) {
            int row = r * 64 + (tid >> 2);
            int chunk = tid & 3;
            gld_lds16(A + (size_t)(row0 + row) * DIM + k0 + chunk * 8,
                      As + row * 32 + chunk * 8);
            gld_lds16(BT + (size_t)(col0 + row) * DIM + k0 + chunk * 8,
                      Bs + row * 32 + chunk * 8);
        }
        __syncthreads();

        bf16x8 a_frag[4], b_frag[4];
        #pragma unroll
        for (int i = 0; i < 4; ++i) {
            a_frag[i] = *(const bf16x8*)(As + (wm + i * 16 + fr) * 32 + kg);
            b_frag[i] = *(const bf16x8*)(Bs + (wn + i * 16 + fr) * 32 + kg);
        }
        #pragma unroll
        for (int i = 0; i < 4; ++i)
            #pragma unroll
            for (int j = 0; j < 4; ++j)
                acc[i][j] = __builtin_amdgcn_mfma_f32_16x16x32_bf16(
                    a_frag[i], b_frag[j], acc[i][j], 0, 0, 0);
        __syncthreads();
    }

    int rg = (lane >> 4) * 4;
    #pragma unroll
    for (int i = 0; i < 4; ++i) {
        #pragma unroll
        for (int j = 0; j < 4; ++j) {
            int n = col0 + wn + j * 16 + fr;
            float bv = bias ? bias[n] : 0.0f;
            #pragma unroll
            for (int r = 0; r < 4; ++r) {
                int m = row0 + wm + i * 16 + rg + r;
                Cb[(size_t)m * DIM + n] = f2bf(acc[i][j][r] + bv);
            }
        }
    }
}

// ---------------- el/er from bf16 h: one wave per node ----------------

__global__ __launch_bounds__(256) void eler_kernel(const unsigned short* __restrict__ Hb,
                                                   const float* __restrict__ al,
                                                   const float* __restrict__ ar,
                                                   float* __restrict__ el,
                                                   float* __restrict__ er) {
    int wave = threadIdx.x >> 6;
    int lane = threadIdx.x & 63;
    int v = blockIdx.x * 4 + wave;
    if (v >= NNODES) return;
    int c0 = lane * 4;
    ushort4 h = *(const ushort4*)(Hb + (size_t)v * DIM + c0);
    float4 a = *(const float4*)(al + c0);
    float4 r = *(const float4*)(ar + c0);
    float h0 = bf2f(h.x), h1 = bf2f(h.y), h2 = bf2f(h.z), h3 = bf2f(h.w);
    float x = h0 * a.x + h1 * a.y + h2 * a.z + h3 * a.w;
    float y = h0 * r.x + h1 * r.y + h2 * r.z + h3 * r.w;
    #pragma unroll
    for (int off = 1; off < 8; off <<= 1) {
        x += __shfl_xor(x, off, 64);
        y += __shfl_xor(y, off, 64);
    }
    if ((lane & 7) == 0) {
        int head = lane >> 3;
        el[v * NHEAD + head] = x;
        er[v * NHEAD + head] = y;
    }
}

// ---------------- edge softmax + aggregation: one wave per dst node ----------------
// No max-subtraction: e = leaky(el+er) is bounded (|e| < ~8), exp() cannot
// overflow, and exp(e)/sum(exp(e)) == exp(e-m)/sum(exp(e-m)) exactly in math.

__global__ __launch_bounds__(256) void agg_kernel(const unsigned short* __restrict__ Hb,
                                                  const float* __restrict__ el,
                                                  const float* __restrict__ er,
                                                  const int* __restrict__ rowptr,
                                                  const int* __restrict__ csr,
                                                  const float* __restrict__ bias,
                                                  float* __restrict__ outf,
                                                  unsigned short* __restrict__ outb) {
    int wave = threadIdx.x >> 6;
    int lane = threadIdx.x & 63;
    int v = blockIdx.x * 4 + wave;
    if (v >= NNODES) return;
    int head = lane >> 3;
    int c0 = lane * 4;

    float er_v = er[v * NHEAD + head];
    float el_v = el[v * NHEAD + head];
    int beg = rowptr[v], end = rowptr[v + 1];

    // self loop
    float w = __expf(leaky(el_v + er_v));
    float z = w;
    float acc0, acc1, acc2, acc3;
    {
        ushort4 h = *(const ushort4*)(Hb + (size_t)v * DIM + c0);
        acc0 = w * bf2f(h.x); acc1 = w * bf2f(h.y);
        acc2 = w * bf2f(h.z); acc3 = w * bf2f(h.w);
    }

    #pragma unroll 2
    for (int i = beg; i < end; ++i) {
        int u = csr[i];
        float e = leaky(el[u * NHEAD + head] + er_v);
        float wi = __expf(e);
        z += wi;
        ushort4 h = *(const ushort4*)(Hb + (size_t)u * DIM + c0);
        acc0 += wi * bf2f(h.x); acc1 += wi * bf2f(h.y);
        acc2 += wi * bf2f(h.z); acc3 += wi * bf2f(h.w);
    }

    float inv = 1.0f / z;
    float4 b = *(const float4*)(bias + c0);
    float o0 = leaky(acc0 * inv + b.x);
    float o1 = leaky(acc1 * inv + b.y);
    float o2 = leaky(acc2 * inv + b.z);
    float o3 = leaky(acc3 * inv + b.w);
    if (outf) {
        float4 o = { o0, o1, o2, o3 };
        *(float4*)(outf + (size_t)v * DIM + c0) = o;
    } else {
        u16x4 o;
        o.x = f2bf(o0); o.y = f2bf(o1); o.z = f2bf(o2); o.w = f2bf(o3);
        *(u16x4*)(outb + (size_t)v * DIM + c0) = o;
    }
}

// ---------------- launch ----------------

static inline size_t align256(size_t x) { return (x + 255) & ~(size_t)255; }

extern "C" void kernel_launch(void* const* d_in, const int* in_sizes, int n_in,
                              void* d_out, int out_size, void* d_ws, size_t ws_size,
                              hipStream_t stream) {
    const float* feats  = (const float*)d_in[0];
    const int*   src    = (const int*)d_in[1];
    const int*   dst    = (const int*)d_in[2];
    const float* proj_W = (const float*)d_in[3];
    const float* proj_b = (const float*)d_in[4];
    const float* W1     = (const float*)d_in[5];
    const float* al1    = (const float*)d_in[6];
    const float* ar1    = (const float*)d_in[7];
    const float* b1     = (const float*)d_in[8];
    const float* W2     = (const float*)d_in[9];
    const float* al2    = (const float*)d_in[10];
    const float* ar2    = (const float*)d_in[11];
    const float* b2     = (const float*)d_in[12];
    float* out = (float*)d_out;

    uint8_t* w = (uint8_t*)d_ws;
    unsigned short* Abf = (unsigned short*)w; w += align256((size_t)MPAD * DIM * 2);
    unsigned short* Bbf = (unsigned short*)w; w += align256((size_t)MPAD * DIM * 2);
    unsigned short* Hb  = (unsigned short*)w; w += align256((size_t)MPAD * DIM * 2);
    unsigned short* WT  = (unsigned short*)w; w += align256((size_t)DIM * DIM * 2);
    float* el = (float*)w;            w += align256((size_t)NNODES * NHEAD * 4);
    float* er = (float*)w;            w += align256((size_t)NNODES * NHEAD * 4);
    int* deg    = (int*)w;            w += align256((size_t)NNODES * 4);
    int* rowptr = (int*)w;            w += align256((size_t)(NNODES + 1) * 4);
    int* cursor = (int*)w;            w += align256((size_t)NNODES * 4);
    int* csr    = (int*)w;            w += align256((size_t)NEDGES * 4);
    int* bsum   = (int*)w;            w += align256((size_t)SCAN_BLOCKS * 4);
    int* boff   = (int*)w;            w += align256((size_t)SCAN_BLOCKS * 4);

    const int edge_blocks = (NEDGES + 255) / 256;
    const dim3 gemm_grid(MPAD / 128, DIM / 128);
    const int node_wave_blocks = (NNODES + 3) / 4;  // one wave per node

    // CSR build
    hipMemsetAsync(deg, 0, (size_t)NNODES * 4, stream);
    count_kernel<<<edge_blocks, 256, 0, stream>>>(dst, deg);
    scanA_kernel<<<SCAN_BLOCKS, 256, 0, stream>>>(deg, bsum);
    scanB_kernel<<<1, 256, 0, stream>>>(bsum, boff, rowptr);
    scanC_kernel<<<SCAN_BLOCKS, 256, 0, stream>>>(deg, boff, rowptr, cursor);
    fill_kernel<<<edge_blocks, 256, 0, stream>>>(src, dst, cursor, csr);

    // projection: Bbf = bf16(feats @ proj_W + proj_b)
    cvt_kernel<<<NNODES * DIM / 1024, 256, 0, stream>>>(feats, Abf);
    transpose_cvt<<<dim3(8, 8), 256, 0, stream>>>(proj_W, WT);
    gemm_kernel<<<gemm_grid, 256, 0, stream>>>(Abf, WT, Bbf, proj_b);

    // layer 1: Hb = Bbf @ W1 ; agg -> Abf (bf16, input of layer-2 gemm)
    transpose_cvt<<<dim3(8, 8), 256, 0, stream>>>(W1, WT);
    gemm_kernel<<<gemm_grid, 256, 0, stream>>>(Bbf, WT, Hb, nullptr);
    eler_kernel<<<node_wave_blocks, 256, 0, stream>>>(Hb, al1, ar1, el, er);
    agg_kernel<<<node_wave_blocks, 256, 0, stream>>>(Hb, el, er, rowptr, csr, b1,
                                                     nullptr, Abf);

    // layer 2: Hb = Abf @ W2 ; agg -> out (fp32)
    transpose_cvt<<<dim3(8, 8), 256, 0, stream>>>(W2, WT);
    gemm_kernel<<<gemm_grid, 256, 0, stream>>>(Abf, WT, Hb, nullptr);
    eler_kernel<<<node_wave_blocks, 256, 0, stream>>>(Hb, al2, ar2, el, er);
    agg_kernel<<<node_wave_blocks, 256, 0, stream>>>(Hb, el, er, rowptr, csr, b2,
                                                     out, nullptr);
}